// Round 2
// baseline (3141.635 us; speedup 1.0000x reference)
//
#include <hip/hip_runtime.h>

#define HH 200
#define WW 200
#define HWSZ 40000
#define BATCH 2
#define C3C 256
#define HEADS 8
#define HD 32
#define PADW 3
#define NPIX 80000

__device__ __forceinline__ float relu_f(float x) { return fmaxf(x, 0.0f); }

// ---------------------------------------------------------------------------
// Generic 1x1-conv GEMM: Out[b, m0+.., hw0+..] (+)= sum_k W[m,k]*In[b,k,hw] (+bias)
// W element address: Wm[m*wm_s + k*wk_s]
// flags: bit0 = accumulate into Out, bit1 = relu
// Tile: 64 c_out x 64 pixels, 256 threads, each 4x4.
// ---------------------------------------------------------------------------
__global__ __launch_bounds__(256) void gemm1x1(
    const float* __restrict__ In, const float* __restrict__ Wm,
    float* __restrict__ Out, const float* __restrict__ bias,
    int C_in, int C_out, int wm_s, int wk_s, int flags)
{
    __shared__ float In_lds[16][64];
    __shared__ float W_lds[16][68];

    const int b   = blockIdx.z;
    const int hw0 = blockIdx.x * 64;
    const int m0  = blockIdx.y * 64;
    const int t   = threadIdx.x;
    const int tx  = t & 15, ty = t >> 4;

    float acc[4][4] = {};
    const float* Inb = In + (size_t)b * C_in * HWSZ + hw0;

    for (int k0 = 0; k0 < C_in; k0 += 16) {
        #pragma unroll
        for (int r = 0; r < 4; ++r) {
            int l = t + r * 256;
            int k = l >> 6, p = l & 63;
            In_lds[k][p] = Inb[(size_t)(k0 + k) * HWSZ + p];
        }
        if (wk_s == 1) {
            #pragma unroll
            for (int r = 0; r < 4; ++r) {
                int l = t + r * 256;
                int k = l & 15, m = l >> 4;
                W_lds[k][m] = Wm[(size_t)(m0 + m) * wm_s + (size_t)(k0 + k)];
            }
        } else {
            #pragma unroll
            for (int r = 0; r < 4; ++r) {
                int l = t + r * 256;
                int m = l & 63, k = l >> 6;
                W_lds[k][m] = Wm[(size_t)(m0 + m) + (size_t)(k0 + k) * wk_s];
            }
        }
        __syncthreads();
        #pragma unroll
        for (int k = 0; k < 16; ++k) {
            const float4 wv = *(const float4*)&W_lds[k][ty * 4];
            const float4 iv = *(const float4*)&In_lds[k][tx * 4];
            acc[0][0] += wv.x * iv.x; acc[0][1] += wv.x * iv.y;
            acc[0][2] += wv.x * iv.z; acc[0][3] += wv.x * iv.w;
            acc[1][0] += wv.y * iv.x; acc[1][1] += wv.y * iv.y;
            acc[1][2] += wv.y * iv.z; acc[1][3] += wv.y * iv.w;
            acc[2][0] += wv.z * iv.x; acc[2][1] += wv.z * iv.y;
            acc[2][2] += wv.z * iv.z; acc[2][3] += wv.z * iv.w;
            acc[3][0] += wv.w * iv.x; acc[3][1] += wv.w * iv.y;
            acc[3][2] += wv.w * iv.z; acc[3][3] += wv.w * iv.w;
        }
        __syncthreads();
    }

    #pragma unroll
    for (int i = 0; i < 4; ++i) {
        const int m = m0 + ty * 4 + i;
        const float bv = bias ? bias[m] : 0.0f;
        float* op = Out + ((size_t)b * C_out + m) * HWSZ + hw0 + tx * 4;
        float4 r;
        r.x = acc[i][0] + bv; r.y = acc[i][1] + bv;
        r.z = acc[i][2] + bv; r.w = acc[i][3] + bv;
        if (flags & 1) {
            const float4 p = *(const float4*)op;
            r.x += p.x; r.y += p.y; r.z += p.z; r.w += p.w;
        }
        if (flags & 2) {
            r.x = relu_f(r.x); r.y = relu_f(r.y);
            r.z = relu_f(r.z); r.w = relu_f(r.w);
        }
        *(float4*)op = r;
    }
}

// ---------------------------------------------------------------------------
// 7x7 local-window attention, replicate padding (index clamp).
// NOTE: A may alias Q (in-place). Each block reads only its own Q region
// (no halo) into registers before writing A there — safe. No __restrict__
// on Q/A for this reason.
// ---------------------------------------------------------------------------
__global__ __launch_bounds__(256) void attn_win(
    const float* Q, const float* __restrict__ K,
    const float* __restrict__ V, float* A)
{
    __shared__ float kv[32][22][22];   // 61952 B

    const int b    = blockIdx.z;
    const int head = blockIdx.y;
    const int tiy  = blockIdx.x / 13, tix = blockIdx.x % 13;
    const int h0   = tiy * 16, w0 = tix * 16;
    const int t    = threadIdx.x;
    const int tx   = t & 15, ty = t >> 4;
    const int h    = h0 + ty, w = w0 + tx;
    const bool valid = (h < HH) && (w < WW);
    const size_t cbase = ((size_t)b * C3C + head * HD) * HWSZ;

    float q[HD];
    if (valid) {
        const float* qp = Q + cbase + h * WW + w;
        #pragma unroll
        for (int c = 0; c < HD; ++c) q[c] = qp[(size_t)c * HWSZ];
    } else {
        #pragma unroll
        for (int c = 0; c < HD; ++c) q[c] = 0.0f;
    }

    for (int l = t; l < 32 * 484; l += 256) {
        int c  = l / 484;
        int rr = l - c * 484;
        int dy = rr / 22, dx = rr - dy * 22;
        int gh = min(max(h0 + dy - PADW, 0), HH - 1);
        int gw = min(max(w0 + dx - PADW, 0), WW - 1);
        ((float*)kv)[l] = K[cbase + (size_t)c * HWSZ + gh * WW + gw];
    }
    __syncthreads();

    float lg[49];
    #pragma unroll
    for (int i = 0; i < 7; ++i) {
        #pragma unroll
        for (int j = 0; j < 7; ++j) {
            float s = 0.0f;
            #pragma unroll
            for (int c = 0; c < HD; ++c) s += q[c] * kv[c][ty + i][tx + j];
            lg[i * 7 + j] = s * 0.17677669529663687f;  // 32^-0.5
        }
    }
    float mx = lg[0];
    #pragma unroll
    for (int n = 1; n < 49; ++n) mx = fmaxf(mx, lg[n]);
    float sum = 0.0f;
    #pragma unroll
    for (int n = 0; n < 49; ++n) { lg[n] = __expf(lg[n] - mx); sum += lg[n]; }
    const float inv = 1.0f / sum;

    __syncthreads();
    for (int l = t; l < 32 * 484; l += 256) {
        int c  = l / 484;
        int rr = l - c * 484;
        int dy = rr / 22, dx = rr - dy * 22;
        int gh = min(max(h0 + dy - PADW, 0), HH - 1);
        int gw = min(max(w0 + dx - PADW, 0), WW - 1);
        ((float*)kv)[l] = V[cbase + (size_t)c * HWSZ + gh * WW + gw];
    }
    __syncthreads();

    float o[HD];
    #pragma unroll
    for (int c = 0; c < HD; ++c) o[c] = 0.0f;
    #pragma unroll
    for (int i = 0; i < 7; ++i) {
        #pragma unroll
        for (int j = 0; j < 7; ++j) {
            const float p = lg[i * 7 + j];
            #pragma unroll
            for (int c = 0; c < HD; ++c) o[c] += p * kv[c][ty + i][tx + j];
        }
    }
    if (valid) {
        float* ap = A + cbase + h * WW + w;
        #pragma unroll
        for (int c = 0; c < HD; ++c) ap[(size_t)c * HWSZ] = o[c] * inv;
    }
}

// ---------------------------------------------------------------------------
// LayerNorm over channels (NCHW). One thread per pixel. No __restrict__:
// callers may alias Out with X/X2 (same-thread read-then-write is safe).
// ---------------------------------------------------------------------------
__global__ __launch_bounds__(256) void layernorm_k(
    const float* X, const float* X2,
    const float* g, const float* bt, float* Out)
{
    const int pix = blockIdx.x * 256 + threadIdx.x;
    if (pix >= NPIX) return;
    const int b  = pix / HWSZ;
    const int hw = pix - b * HWSZ;
    const size_t base = (size_t)b * C3C * HWSZ + hw;

    float s = 0.0f, ss = 0.0f;
    for (int c = 0; c < C3C; ++c) {
        float x = X[base + (size_t)c * HWSZ];
        if (X2) x += X2[base + (size_t)c * HWSZ];
        s += x; ss += x * x;
    }
    const float mu  = s * (1.0f / C3C);
    const float var = ss * (1.0f / C3C) - mu * mu;
    const float rs  = rsqrtf(var + 1e-5f);
    for (int c = 0; c < C3C; ++c) {
        float x = X[base + (size_t)c * HWSZ];
        if (X2) x += X2[base + (size_t)c * HWSZ];
        Out[base + (size_t)c * HWSZ] = (x - mu) * rs * g[c] + bt[c];
    }
}

// ---------------------------------------------------------------------------
// Workspace plan (NB = 20.48M floats = 81.92 MB; total d_ws use = 3*NB = 245.8 MB):
//   ws0: Q  -> A (in-place in attn) -> Y1 chunk (FFN hidden, 256ch at a time)
//   ws1: K  -> XL (LN1 output)
//   ws2: V  -> Y2 (FFN output accumulator)
//   d_out:  XW (out-proj + residual scratch) -> final LN2 output
// ---------------------------------------------------------------------------
extern "C" void kernel_launch(void* const* d_in, const int* in_sizes, int n_in,
                              void* d_out, int out_size, void* d_ws, size_t ws_size,
                              hipStream_t stream)
{
    const float* F_lidar = (const float*)d_in[0];
    const float* F_cam   = (const float*)d_in[1];
    const float* Wq  = (const float*)d_in[2];
    const float* Wk  = (const float*)d_in[3];
    const float* Wv  = (const float*)d_in[4];
    const float* Wo  = (const float*)d_in[5];
    const float* Wr  = (const float*)d_in[6];
    const float* g1  = (const float*)d_in[7];
    const float* b1  = (const float*)d_in[8];
    const float* g2  = (const float*)d_in[9];
    const float* b2  = (const float*)d_in[10];
    const float* W1  = (const float*)d_in[11];
    const float* bf1 = (const float*)d_in[12];
    const float* W2  = (const float*)d_in[13];
    const float* bf2 = (const float*)d_in[14];
    float* out = (float*)d_out;
    float* ws  = (float*)d_ws;

    const size_t NB = (size_t)BATCH * C3C * HWSZ;   // 20,480,000 floats
    float* ws0 = ws;
    float* ws1 = ws + NB;
    float* ws2 = ws + 2 * NB;

    const dim3 blk(256);

    // projections
    gemm1x1<<<dim3(625, 4, 2), blk, 0, stream>>>(F_lidar, Wq, ws0, nullptr, 64, 256, 64, 1, 0);
    gemm1x1<<<dim3(625, 4, 2), blk, 0, stream>>>(F_cam,  Wk, ws1, nullptr, 256, 256, 256, 1, 0);
    gemm1x1<<<dim3(625, 4, 2), blk, 0, stream>>>(F_cam,  Wv, ws2, nullptr, 256, 256, 256, 1, 0);

    // local-window attention: A overwrites Q (in-place, block-local regions)
    attn_win<<<dim3(169, 8, 2), blk, 0, stream>>>(ws0, ws1, ws2, ws0);

    // output projection + lidar residual -> XW in d_out
    gemm1x1<<<dim3(625, 4, 2), blk, 0, stream>>>(ws0, Wo, out, nullptr, 256, 256, 256, 1, 0);
    gemm1x1<<<dim3(625, 4, 2), blk, 0, stream>>>(F_lidar, Wr, out, nullptr, 64, 256, 64, 1, 1);

    // LN1: XL <- LN(XW)   (K buffer dead)
    layernorm_k<<<dim3(313), blk, 0, stream>>>(out, nullptr, g1, b1, ws1);

    // FFN, hidden dim chunked 4 x 256:
    //   Yc = relu(XL @ W1[:,Hc] + bf1[Hc])   -> ws0 (Q/A dead)
    //   Y2 (+)= Yc @ W2[Hc,:] (+bf2 on c=0)  -> ws2 (V dead)
    for (int c = 0; c < 4; ++c) {
        gemm1x1<<<dim3(625, 4, 2), blk, 0, stream>>>(
            ws1, W1 + c * 256, ws0, bf1 + c * 256, 256, 256, 1, 1024, 2);
        gemm1x1<<<dim3(625, 4, 2), blk, 0, stream>>>(
            ws0, W2 + (size_t)c * 256 * 256, ws2, (c == 0) ? bf2 : nullptr,
            256, 256, 1, 256, (c == 0) ? 0 : 1);
    }

    // LN2 (XL + Y2) -> final output (XW in d_out is dead by now)
    layernorm_k<<<dim3(313), blk, 0, stream>>>(ws1, ws2, g2, b2, out);
}

// Round 3
// 1029.967 us; speedup vs baseline: 3.0502x; 3.0502x over previous
//
#include <hip/hip_runtime.h>
#include <stdint.h>

#define HH 200
#define WW 200
#define HWSZ 40000
#define NPX 80000

typedef __attribute__((ext_vector_type(8))) short bf16x8;
typedef __attribute__((ext_vector_type(4))) float f32x4;

__device__ __forceinline__ float bf2f(unsigned short u) {
    union { uint32_t i; float f; } c; c.i = ((uint32_t)u) << 16; return c.f;
}
__device__ __forceinline__ unsigned short f2bf(float f) {
    union { float f; uint32_t i; } c; c.f = f;
    uint32_t r = c.i + 0x7FFF + ((c.i >> 16) & 1);   // RNE
    return (unsigned short)(r >> 16);
}

// ---------------------------------------------------------------------------
// Weight conversion: fp32 -> bf16; W1/W2 transposed to [cout][cin];
// Wcat = concat(Wo, Wr) along k (k<256 -> Wo, k>=256 -> Wr).
// ---------------------------------------------------------------------------
__global__ __launch_bounds__(256) void cvt_weights(
    const float* __restrict__ Wq, const float* __restrict__ Wk,
    const float* __restrict__ Wv, const float* __restrict__ Wo,
    const float* __restrict__ Wr, const float* __restrict__ W1,
    const float* __restrict__ W2,
    unsigned short* Wq_b, unsigned short* Wk_b, unsigned short* Wv_b,
    unsigned short* Wcat, unsigned short* W1t, unsigned short* W2t)
{
    const int seg = blockIdx.y;
    const int idx = blockIdx.x * 256 + threadIdx.x;
    if (seg == 0)      { if (idx < 16384) Wq_b[idx] = f2bf(Wq[idx]); }
    else if (seg == 1) { if (idx < 65536) Wk_b[idx] = f2bf(Wk[idx]); }
    else if (seg == 2) { if (idx < 65536) Wv_b[idx] = f2bf(Wv[idx]); }
    else if (seg == 3) {
        if (idx < 81920) {
            int r = idx / 320, k = idx - r * 320;
            Wcat[idx] = f2bf(k < 256 ? Wo[r * 256 + k] : Wr[r * 64 + (k - 256)]);
        }
    } else if (seg == 4) {
        if (idx < 262144) { int o = idx >> 8, i = idx & 255; W1t[idx] = f2bf(W1[i * 1024 + o]); }
    } else {
        if (idx < 262144) { int o = idx >> 10, i = idx & 1023; W2t[idx] = f2bf(W2[i * 256 + o]); }
    }
}

// ---------------------------------------------------------------------------
// NCHW fp32 -> NHWC bf16 (64px x 64c LDS tile).
// ---------------------------------------------------------------------------
__global__ __launch_bounds__(256) void to_nhwc(
    const float* __restrict__ src, unsigned short* __restrict__ dst, int C)
{
    __shared__ unsigned short T[64][72];
    const int b = blockIdx.z, c0 = blockIdx.y * 64, px0 = blockIdx.x * 64;
    const int t = threadIdx.x;
    const int pxl = t & 63, cl0 = t >> 6;
    const float* sp = src + ((size_t)(b * C + c0 + cl0)) * HWSZ + px0 + pxl;
    #pragma unroll
    for (int i = 0; i < 16; ++i)
        T[pxl][cl0 + i * 4] = f2bf(sp[(size_t)i * 4 * HWSZ]);
    __syncthreads();
    #pragma unroll
    for (int r = 0; r < 2; ++r) {
        int idx = t + r * 256;
        int p = idx >> 3, cof = (idx & 7) * 8;
        uint4 v = *(const uint4*)&T[p][cof];
        *(uint4*)(dst + ((size_t)(b * HWSZ + px0 + p)) * C + c0 + cof) = v;
    }
}

// ---------------------------------------------------------------------------
// bf16 MFMA GEMM (NHWC activations x row-major [cout][cin] weights).
// Out[px][cout] = sum_k In[px][k] * W[cout][k]; M=80000, tile 128x128, BK=32.
// Optional concat second input (k >= K1 -> In2). Out: bf16 (OutB) or fp32
// (OutF). flags: 1=relu, 2=fp32 accumulate. Out row stride fixed at 256.
// LDS is staged in MFMA *fragment order*: frag block = 64 lanes x 16B, so
// both staging stores and ds_read_b128 fragment reads are lane-contiguous.
// ---------------------------------------------------------------------------
__global__ __launch_bounds__(256) void gemm_bf16(
    const unsigned short* __restrict__ In, int inStride,
    const unsigned short* __restrict__ In2, int in2Stride, int K1,
    const unsigned short* __restrict__ Wb, int wStride, int Ktot,
    unsigned short* __restrict__ OutB, float* __restrict__ OutF,
    const float* __restrict__ bias, int flags)
{
    __shared__ bf16x8 AB[1024];   // [0..511] A frags, [512..1023] B frags
    const int t = threadIdx.x;
    const int px0 = blockIdx.x * 128;
    const int n0 = blockIdx.y * 128;
    const int lane = t & 63, w = t >> 6;
    const int mh = w & 1, nh = w >> 1;

    f32x4 acc[4][4] = {};

    for (int k0 = 0; k0 < Ktot; k0 += 32) {
        #pragma unroll
        for (int r = 0; r < 2; ++r) {
            const int c = t + r * 256;
            const int l = c & 63;
            const int ko = k0 + ((l >> 4) << 3);
            // A frag chunk: lane holds In[px0 + mt*16 + (l&15)][ko..ko+7]
            {
                const int mt = c >> 6;
                const int px = px0 + mt * 16 + (l & 15);
                const unsigned short* sp = (ko < K1)
                    ? (In  + (size_t)px * inStride  + ko)
                    : (In2 + (size_t)px * in2Stride + (ko - K1));
                AB[c] = *(const bf16x8*)sp;
            }
            // B frag chunk: lane holds W[n0 + nt*16 + (l&15)][ko..ko+7]
            {
                const int nt = c >> 6;
                const int cc = n0 + nt * 16 + (l & 15);
                AB[512 + c] = *(const bf16x8*)(Wb + (size_t)cc * wStride + ko);
            }
        }
        __syncthreads();
        bf16x8 av[4], bv[4];
        #pragma unroll
        for (int i = 0; i < 4; ++i) av[i] = AB[(mh * 4 + i) * 64 + lane];
        #pragma unroll
        for (int j = 0; j < 4; ++j) bv[j] = AB[512 + (nh * 4 + j) * 64 + lane];
        #pragma unroll
        for (int i = 0; i < 4; ++i)
            #pragma unroll
            for (int j = 0; j < 4; ++j)
                acc[i][j] = __builtin_amdgcn_mfma_f32_16x16x32_bf16(
                    av[i], bv[j], acc[i][j], 0, 0, 0);
        __syncthreads();
    }

    const int q = lane >> 4, ln = lane & 15;
    const bool relu = (flags & 1) != 0, accum = (flags & 2) != 0;
    #pragma unroll
    for (int i = 0; i < 4; ++i) {
        #pragma unroll
        for (int j = 0; j < 4; ++j) {
            const int coutv = n0 + nh * 64 + j * 16 + ln;
            const float bval = bias ? bias[coutv] : 0.0f;
            #pragma unroll
            for (int r = 0; r < 4; ++r) {
                const int px = px0 + mh * 64 + i * 16 + q * 4 + r;
                float v = acc[i][j][r] + bval;
                if (relu) v = fmaxf(v, 0.0f);
                if (OutB) {
                    OutB[(size_t)px * 256 + coutv] = f2bf(v);
                } else {
                    float* op = OutF + (size_t)px * 256 + coutv;
                    if (accum) v += *op;
                    *op = v;
                }
            }
        }
    }
}

// ---------------------------------------------------------------------------
// 7x7 local-window attention, NHWC bf16, replicate pad via clamp.
// Block = (b, head, 16x16 px tile); LDS = 22x22 halo x 32c (pad to 40) bf16.
// A may alias Q (in-place): each block reads only its own Q region. ds_read
// is 4x b128 per window tap (c-contiguous), 80B row stride -> 2-way max.
// ---------------------------------------------------------------------------
__global__ __launch_bounds__(256) void attn_bf16(
    const unsigned short* Q, const unsigned short* __restrict__ K,
    const unsigned short* __restrict__ V, unsigned short* A)
{
    __shared__ __align__(16) unsigned short kv[484 * 40];   // 38720 B
    const int b = blockIdx.z, head = blockIdx.y;
    const int tiy = blockIdx.x / 13, tix = blockIdx.x % 13;
    const int h0 = tiy * 16, w0 = tix * 16;
    const int t = threadIdx.x, tx = t & 15, ty = t >> 4;
    const int h = h0 + ty, wq = w0 + tx;
    const bool valid = (h < HH) && (wq < WW);
    const int co = head * 32;

    float qv[32];
    if (valid) {
        const unsigned short* qp = Q + ((size_t)(b * HWSZ + h * WW + wq)) * 256 + co;
        #pragma unroll
        for (int cc = 0; cc < 4; ++cc) {
            bf16x8 qq = *(const bf16x8*)(qp + cc * 8);
            #pragma unroll
            for (int e = 0; e < 8; ++e) qv[cc * 8 + e] = bf2f((unsigned short)qq[e]);
        }
    } else {
        #pragma unroll
        for (int c = 0; c < 32; ++c) qv[c] = 0.0f;
    }

    for (int idx = t; idx < 484 * 4; idx += 256) {
        int rr = idx >> 2, ch = idx & 3;
        int dy = rr / 22, dx = rr - dy * 22;
        int gh = min(max(h0 + dy - 3, 0), HH - 1);
        int gw = min(max(w0 + dx - 3, 0), WW - 1);
        *(bf16x8*)&kv[rr * 40 + ch * 8] =
            *(const bf16x8*)(K + ((size_t)(b * HWSZ + gh * WW + gw)) * 256 + co + ch * 8);
    }
    __syncthreads();

    float lg[49];
    #pragma unroll
    for (int i = 0; i < 7; ++i)
        #pragma unroll
        for (int j = 0; j < 7; ++j) {
            const unsigned short* kp = &kv[((ty + i) * 22 + (tx + j)) * 40];
            float s = 0.0f;
            #pragma unroll
            for (int cc = 0; cc < 4; ++cc) {
                bf16x8 kk = *(const bf16x8*)(kp + cc * 8);
                #pragma unroll
                for (int e = 0; e < 8; ++e)
                    s += qv[cc * 8 + e] * bf2f((unsigned short)kk[e]);
            }
            lg[i * 7 + j] = s * 0.17677669529663687f;   // 32^-0.5
        }

    float mx = lg[0];
    #pragma unroll
    for (int n = 1; n < 49; ++n) mx = fmaxf(mx, lg[n]);
    float sum = 0.0f;
    #pragma unroll
    for (int n = 0; n < 49; ++n) { lg[n] = __expf(lg[n] - mx); sum += lg[n]; }
    const float inv = 1.0f / sum;

    __syncthreads();
    for (int idx = t; idx < 484 * 4; idx += 256) {
        int rr = idx >> 2, ch = idx & 3;
        int dy = rr / 22, dx = rr - dy * 22;
        int gh = min(max(h0 + dy - 3, 0), HH - 1);
        int gw = min(max(w0 + dx - 3, 0), WW - 1);
        *(bf16x8*)&kv[rr * 40 + ch * 8] =
            *(const bf16x8*)(V + ((size_t)(b * HWSZ + gh * WW + gw)) * 256 + co + ch * 8);
    }
    __syncthreads();

    float o[32];
    #pragma unroll
    for (int c = 0; c < 32; ++c) o[c] = 0.0f;
    #pragma unroll
    for (int i = 0; i < 7; ++i)
        #pragma unroll
        for (int j = 0; j < 7; ++j) {
            const float p = lg[i * 7 + j];
            const unsigned short* vp = &kv[((ty + i) * 22 + (tx + j)) * 40];
            #pragma unroll
            for (int cc = 0; cc < 4; ++cc) {
                bf16x8 vv = *(const bf16x8*)(vp + cc * 8);
                #pragma unroll
                for (int e = 0; e < 8; ++e)
                    o[cc * 8 + e] += p * bf2f((unsigned short)vv[e]);
            }
        }

    if (valid) {
        unsigned short* ap = A + ((size_t)(b * HWSZ + h * WW + wq)) * 256 + co;
        #pragma unroll
        for (int cc = 0; cc < 4; ++cc) {
            bf16x8 ov;
            #pragma unroll
            for (int e = 0; e < 8; ++e) ov[e] = (short)f2bf(o[cc * 8 + e] * inv);
            *(bf16x8*)(ap + cc * 8) = ov;
        }
    }
}

// ---------------------------------------------------------------------------
// LN1: wave-per-pixel over contiguous 256 channels (NHWC fp32 in, bf16 out).
// ---------------------------------------------------------------------------
__global__ __launch_bounds__(256) void ln1_k(
    const float* __restrict__ X, const float* __restrict__ g,
    const float* __restrict__ bt, unsigned short* __restrict__ XLb)
{
    const int wv = threadIdx.x >> 6, lane = threadIdx.x & 63;
    const size_t px = (size_t)blockIdx.x * 4 + wv;
    const float4 v = *(const float4*)(X + px * 256 + lane * 4);
    float s = v.x + v.y + v.z + v.w;
    float ss = v.x * v.x + v.y * v.y + v.z * v.z + v.w * v.w;
    #pragma unroll
    for (int o = 32; o; o >>= 1) { s += __shfl_xor(s, o); ss += __shfl_xor(ss, o); }
    const float mu = s * (1.0f / 256.0f);
    const float var = ss * (1.0f / 256.0f) - mu * mu;
    const float rs = rsqrtf(var + 1e-5f);
    const float4 gv = *(const float4*)(g + lane * 4);
    const float4 bv = *(const float4*)(bt + lane * 4);
    ushort4 o4;
    o4.x = f2bf((v.x - mu) * rs * gv.x + bv.x);
    o4.y = f2bf((v.y - mu) * rs * gv.y + bv.y);
    o4.z = f2bf((v.z - mu) * rs * gv.z + bv.z);
    o4.w = f2bf((v.w - mu) * rs * gv.w + bv.w);
    *(ushort4*)(XLb + px * 256 + lane * 4) = o4;
}

// ---------------------------------------------------------------------------
// LN2: (bf16 XL + fp32 Y2) -> LN -> NCHW fp32 out, via LDS transpose.
// Block = 32 pixels; wave-per-pixel stats, then coalesced NCHW row writes.
// ---------------------------------------------------------------------------
__global__ __launch_bounds__(256) void ln2_k(
    const unsigned short* __restrict__ XLb, const float* __restrict__ Y2,
    const float* __restrict__ g, const float* __restrict__ bt,
    float* __restrict__ Out)
{
    __shared__ float T[256 * 33];
    const int px0 = blockIdx.x * 32;
    const int bb = px0 / HWSZ, hw0 = px0 - bb * HWSZ;
    const int t = threadIdx.x, wv = t >> 6, lane = t & 63;
    const float4 gv = *(const float4*)(g + lane * 4);
    const float4 bv = *(const float4*)(bt + lane * 4);
    #pragma unroll
    for (int it = 0; it < 8; ++it) {
        const int pxl = wv * 8 + it;
        const size_t px = (size_t)px0 + pxl;
        const ushort4 xb = *(const ushort4*)(XLb + px * 256 + lane * 4);
        const float4 y = *(const float4*)(Y2 + px * 256 + lane * 4);
        float4 v;
        v.x = bf2f(xb.x) + y.x; v.y = bf2f(xb.y) + y.y;
        v.z = bf2f(xb.z) + y.z; v.w = bf2f(xb.w) + y.w;
        float s = v.x + v.y + v.z + v.w;
        float ss = v.x * v.x + v.y * v.y + v.z * v.z + v.w * v.w;
        #pragma unroll
        for (int o = 32; o; o >>= 1) { s += __shfl_xor(s, o); ss += __shfl_xor(ss, o); }
        const float mu = s * (1.0f / 256.0f);
        const float rs = rsqrtf(ss * (1.0f / 256.0f) - mu * mu + 1e-5f);
        T[(lane * 4 + 0) * 33 + pxl] = (v.x - mu) * rs * gv.x + bv.x;
        T[(lane * 4 + 1) * 33 + pxl] = (v.y - mu) * rs * gv.y + bv.y;
        T[(lane * 4 + 2) * 33 + pxl] = (v.z - mu) * rs * gv.z + bv.z;
        T[(lane * 4 + 3) * 33 + pxl] = (v.w - mu) * rs * gv.w + bv.w;
    }
    __syncthreads();
    #pragma unroll
    for (int pass = 0; pass < 32; ++pass) {
        const int idx = t + pass * 256;
        const int c = idx >> 5, pxl = idx & 31;
        Out[((size_t)(bb * 256 + c)) * HWSZ + hw0 + pxl] = T[c * 33 + pxl];
    }
}

// ---------------------------------------------------------------------------
// Workspace (bytes):                                      total 216.6 MB
//   0         : Fl_bf  [80000][64]  bf16   (10.24 MB)
//   10240000  : Fc_bf  [80000][256] bf16   (40.96) -> Y1 chunk later
//   51200000  : Qb/Ab  [80000][256] bf16   (40.96, attn in-place)
//   92160000  : Kb, Vb [2x 40.96]          -> Y2 fp32 [80000][256] (81.92)
//   174080000 : XLb    [80000][256] bf16   (40.96)
//   215040000 : bf16 weights (~1.5 MB)
//   d_out     : XW fp32 NHWC scratch, then final NCHW output
// ---------------------------------------------------------------------------
extern "C" void kernel_launch(void* const* d_in, const int* in_sizes, int n_in,
                              void* d_out, int out_size, void* d_ws, size_t ws_size,
                              hipStream_t stream)
{
    const float* F_lidar = (const float*)d_in[0];
    const float* F_cam   = (const float*)d_in[1];
    const float* Wq  = (const float*)d_in[2];
    const float* Wk  = (const float*)d_in[3];
    const float* Wv  = (const float*)d_in[4];
    const float* Wo  = (const float*)d_in[5];
    const float* Wr  = (const float*)d_in[6];
    const float* g1  = (const float*)d_in[7];
    const float* b1  = (const float*)d_in[8];
    const float* g2  = (const float*)d_in[9];
    const float* b2  = (const float*)d_in[10];
    const float* W1  = (const float*)d_in[11];
    const float* bf1 = (const float*)d_in[12];
    const float* W2  = (const float*)d_in[13];
    const float* bf2 = (const float*)d_in[14];

    char* wsb = (char*)d_ws;
    unsigned short* Fl  = (unsigned short*)(wsb);
    unsigned short* Fc  = (unsigned short*)(wsb + 10240000);
    unsigned short* Qb  = (unsigned short*)(wsb + 51200000);
    unsigned short* Kb  = (unsigned short*)(wsb + 92160000);
    unsigned short* Vb  = (unsigned short*)(wsb + 133120000);
    float*          Y2  = (float*)(wsb + 92160000);      // overlays Kb+Vb
    unsigned short* Y1  = Fc;                             // overlays Fc
    unsigned short* XLb = (unsigned short*)(wsb + 174080000);
    unsigned short* Wq_b = (unsigned short*)(wsb + 215040000);
    unsigned short* Wk_b = Wq_b + 16384;
    unsigned short* Wv_b = Wk_b + 65536;
    unsigned short* Wcat = Wv_b + 65536;
    unsigned short* W1t  = Wcat + 81920;
    unsigned short* W2t  = W1t + 262144;
    float* XW  = (float*)d_out;
    float* out = (float*)d_out;

    const dim3 blk(256);

    cvt_weights<<<dim3(1024, 6), blk, 0, stream>>>(Wq, Wk, Wv, Wo, Wr, W1, W2,
        Wq_b, Wk_b, Wv_b, Wcat, W1t, W2t);
    to_nhwc<<<dim3(625, 1, 2), blk, 0, stream>>>(F_lidar, Fl, 64);
    to_nhwc<<<dim3(625, 4, 2), blk, 0, stream>>>(F_cam, Fc, 256);

    // Q/K/V projections (bf16 out)
    gemm_bf16<<<dim3(625, 2), blk, 0, stream>>>(Fl, 64, Fl, 64, 64,
        Wq_b, 64, 64, Qb, nullptr, nullptr, 0);
    gemm_bf16<<<dim3(625, 2), blk, 0, stream>>>(Fc, 256, Fc, 256, 256,
        Wk_b, 256, 256, Kb, nullptr, nullptr, 0);
    gemm_bf16<<<dim3(625, 2), blk, 0, stream>>>(Fc, 256, Fc, 256, 256,
        Wv_b, 256, 256, Vb, nullptr, nullptr, 0);

    // attention (A overwrites Q in-place)
    attn_bf16<<<dim3(169, 8, 2), blk, 0, stream>>>(Qb, Kb, Vb, Qb);

    // fused out-proj + lidar residual: K=320 concat GEMM -> fp32 XW (d_out)
    gemm_bf16<<<dim3(625, 2), blk, 0, stream>>>(Qb, 256, Fl, 64, 256,
        Wcat, 320, 320, nullptr, XW, nullptr, 0);

    // LN1 -> bf16 XLb
    ln1_k<<<dim3(20000), blk, 0, stream>>>(XW, g1, b1, XLb);

    // FFN, hidden chunked 4 x 256
    for (int c = 0; c < 4; ++c) {
        gemm_bf16<<<dim3(625, 2), blk, 0, stream>>>(XLb, 256, XLb, 256, 256,
            W1t + (size_t)c * 65536, 256, 256, Y1, nullptr, bf1 + c * 256, 1);
        gemm_bf16<<<dim3(625, 2), blk, 0, stream>>>(Y1, 256, Y1, 256, 256,
            W2t + c * 256, 1024, 256, nullptr, Y2,
            (c == 0) ? bf2 : nullptr, (c == 0) ? 0 : 2);
    }

    // LN2 (XLb + Y2) -> final NCHW output
    ln2_k<<<dim3(2500), blk, 0, stream>>>(XLb, Y2, g2, b2, out);
}